// Round 1
// baseline (384.098 us; speedup 1.0000x reference)
//
#include <hip/hip_runtime.h>

#define DEVINL __device__ __forceinline__

constexpr int E    = 768;
constexpr int TSEQ = 512;
constexpr int NH   = 12;
constexpr int HD   = 64;
constexpr float RSCALE = 0.036084391824351615f; // 1/sqrt(768)

DEVINL float dot4f(float4 a, float4 b, float acc) {
    acc = fmaf(a.x, b.x, acc);
    acc = fmaf(a.y, b.y, acc);
    acc = fmaf(a.z, b.z, acc);
    acc = fmaf(a.w, b.w, acc);
    return acc;
}

DEVINL float4 fma4(float s, float4 v, float4 acc) {
    acc.x = fmaf(s, v.x, acc.x);
    acc.y = fmaf(s, v.y, acc.y);
    acc.z = fmaf(s, v.z, acc.z);
    acc.w = fmaf(s, v.w, acc.w);
    return acc;
}

// ---------------------------------------------------------------------------
// Kernel 1: QKV projections.  y = x @ W^T + b, stored as [b][h][l][d] fp32.
// 64x64 output tile per block, 256 threads, 4x4 microtile, K-chunk 16.
// ---------------------------------------------------------------------------
__global__ __launch_bounds__(256) void qkv_kernel(
    const float* __restrict__ x,
    const float* __restrict__ wq, const float* __restrict__ bq,
    const float* __restrict__ wk, const float* __restrict__ bk,
    const float* __restrict__ wv, const float* __restrict__ bv,
    float* __restrict__ Qo, float* __restrict__ Ko, float* __restrict__ Vo)
{
    const float* W; const float* bias; float* outp;
    if (blockIdx.z == 0)      { W = wq; bias = bq; outp = Qo; }
    else if (blockIdx.z == 1) { W = wk; bias = bk; outp = Ko; }
    else                      { W = wv; bias = bv; outp = Vo; }

    __shared__ float xs[16][68];   // [k][m], padded
    __shared__ float wls[16][68];  // [k][n], padded

    const int m0  = blockIdx.x * 64;
    const int n0  = blockIdx.y * 64;
    const int tid = threadIdx.x;
    const int tx  = tid & 15;   // n microtile
    const int ty  = tid >> 4;   // m microtile
    const int lr  = tid >> 2;   // load row 0..63
    const int lc  = tid & 3;    // load float4 col 0..3

    float acc[4][4] = {};

    for (int k0 = 0; k0 < E; k0 += 16) {
        float4 xv   = *(const float4*)&x[(size_t)(m0 + lr) * E + k0 + lc * 4];
        float4 wvec = *(const float4*)&W[(size_t)(n0 + lr) * E + k0 + lc * 4];
        __syncthreads();
        xs[lc*4+0][lr] = xv.x;  xs[lc*4+1][lr] = xv.y;
        xs[lc*4+2][lr] = xv.z;  xs[lc*4+3][lr] = xv.w;
        wls[lc*4+0][lr] = wvec.x; wls[lc*4+1][lr] = wvec.y;
        wls[lc*4+2][lr] = wvec.z; wls[lc*4+3][lr] = wvec.w;
        __syncthreads();
        #pragma unroll
        for (int k = 0; k < 16; k++) {
            float4 a4 = *(const float4*)&xs[k][ty*4];
            float4 b4 = *(const float4*)&wls[k][tx*4];
            float av[4] = {a4.x, a4.y, a4.z, a4.w};
            float bw[4] = {b4.x, b4.y, b4.z, b4.w};
            #pragma unroll
            for (int i = 0; i < 4; i++)
                #pragma unroll
                for (int j = 0; j < 4; j++)
                    acc[i][j] = fmaf(av[i], bw[j], acc[i][j]);
        }
    }

    float4 bv4 = *(const float4*)&bias[n0 + tx*4];
    const int bb = m0 / TSEQ;            // tile fully inside one batch (512%64==0)
    const int l  = (m0 % TSEQ) + ty*4;
    const int hh = n0 >> 6;              // tile fully inside one head (64-wide)
    float* ob = outp + ((size_t)(bb*NH + hh) * TSEQ) * HD;
    #pragma unroll
    for (int i = 0; i < 4; i++) {
        float4 r;
        r.x = acc[i][0] + bv4.x;
        r.y = acc[i][1] + bv4.y;
        r.z = acc[i][2] + bv4.z;
        r.w = acc[i][3] + bv4.w;
        *(float4*)&ob[(size_t)(l + i) * HD + tx*4] = r;
    }
}

// ---------------------------------------------------------------------------
// Kernel 2: fold conv1 (and 1/sqrt(E)) into K.
//   Kp[b][h][o][t][d] = (1/scale) * sum_i w1[(h*8+o)*12+i] * K[b][i][t][d]
// One float4 output per thread; (b,h,o) uniform per block.
// ---------------------------------------------------------------------------
__global__ __launch_bounds__(256) void kmix_kernel(
    const float* __restrict__ K,   // [B,12,T,64]
    const float* __restrict__ w1,  // [96,12]
    float* __restrict__ Kp)        // [B,12,8,T,64]
{
    const int g  = blockIdx.x * 256 + threadIdx.x;   // float4 index
    const int d4 = g & 15;
    const int t  = (g >> 4) & 511;
    const int o  = (g >> 13) & 7;
    const int hb = g >> 16;          // b*12 + h
    const int h  = hb % NH;
    const int b  = hb / NH;

    float4 acc = {0.f, 0.f, 0.f, 0.f};
    #pragma unroll
    for (int i = 0; i < 12; i++) {
        float w = w1[(h*8 + o)*12 + i] * RSCALE;
        float4 kv = *(const float4*)&K[(((size_t)(b*NH + i) * TSEQ) + t) * HD + d4*4];
        acc = fma4(w, kv, acc);
    }
    *(float4*)&Kp[(size_t)g * 4] = acc;
}

// ---------------------------------------------------------------------------
// Per-position talking-heads MLP (conv1 already folded into Kp):
//   z1[o]=relu(s[o]+b1[o]); z2=sum z1*w2+b2; a=sum_j relu(z2*w3[j]+b3[j])*w4[j]+b4
// ---------------------------------------------------------------------------
DEVINL float mlp_eval(const float s[8],
                      const float b1r[8], const float w2r[8], float b2r,
                      const float w3r[4], const float b3r[4],
                      const float w4r[4], float b4r)
{
    float z2 = b2r;
    #pragma unroll
    for (int o = 0; o < 8; o++) {
        float z1 = fmaxf(s[o] + b1r[o], 0.0f);
        z2 = fmaf(z1, w2r[o], z2);
    }
    float r = b4r;
    #pragma unroll
    for (int j = 0; j < 4; j++) {
        float z3 = fmaxf(fmaf(z2, w3r[j], b3r[j]), 0.0f);
        r = fmaf(z3, w4r[j], r);
    }
    return r;
}

// ---------------------------------------------------------------------------
// Kernel 3: fused attention. Block = (b, h, 32-row query tile). 256 threads.
// Loop over key tiles of 16:
//   phase1: S'[l,o,t] = Q[l]·Kp[o,t]  (8 dots of 64), MLP -> A[l][t] in LDS
//   phase2: O[l][d] += A[l][t] * V[t][d]
// LDS ~49 KB -> 3 blocks/CU.
// ---------------------------------------------------------------------------
__global__ __launch_bounds__(256) void attn_kernel(
    const float* __restrict__ Q,    // [B,12,T,64]
    const float* __restrict__ Kp,   // [B,12,8,T,64]
    const float* __restrict__ V,    // [B,12,T,64]
    const float* __restrict__ b1, const float* __restrict__ w2,
    const float* __restrict__ b2, const float* __restrict__ w3,
    const float* __restrict__ b3, const float* __restrict__ w4,
    const float* __restrict__ b4,
    float* __restrict__ out)        // [B,T,768]
{
    constexpr int KPAD = 68;                 // padded 64-float row
    __shared__ float Qs[32 * KPAD];
    __shared__ float Ks[8 * 16 * KPAD];
    __shared__ float Vs[16 * KPAD];
    __shared__ float As[32 * 17];

    const int blk = blockIdx.x;              // b*192 + h*16 + lb
    const int lb  = blk & 15;
    const int h   = (blk >> 4) % NH;
    const int b   = blk / (16 * NH);
    const int l0  = lb * 32;
    const int tid = threadIdx.x;
    const int tt  = tid & 15;                // key col within tile / d-chunk
    const int lrw = tid >> 4;                // 0..15 query-row group

    // MLP weights in registers (wave-uniform per block)
    float b1r[8], w2r[8], w3r[4], b3r[4], w4r[4];
    #pragma unroll
    for (int o = 0; o < 8; o++) { b1r[o] = b1[h*8+o]; w2r[o] = w2[h*8+o]; }
    #pragma unroll
    for (int j = 0; j < 4; j++) { w3r[j] = w3[h*4+j]; b3r[j] = b3[h*4+j]; w4r[j] = w4[h*4+j]; }
    const float b2r = b2[h];
    const float b4r = b4[h];

    // Q tile -> LDS (32 rows x 16 float4)
    {
        const float* qb = Q + ((size_t)(b*NH + h) * TSEQ + l0) * HD;
        #pragma unroll
        for (int f = tid; f < 512; f += 256) {
            int r = f >> 4, dd = f & 15;
            float4 v = *(const float4*)&qb[r * HD + dd * 4];
            *(float4*)&Qs[r * KPAD + dd * 4] = v;
        }
    }

    float4 accA = {0.f,0.f,0.f,0.f};
    float4 accB = {0.f,0.f,0.f,0.f};

    const float* kbase = Kp + (size_t)(b*NH + h) * 8 * TSEQ * HD;
    const float* vbase = V  + (size_t)(b*NH + h) * TSEQ * HD;

    for (int t0 = 0; t0 < TSEQ; t0 += 16) {
        // stage Kp tile [8 o][16 t][64 d] and V tile [16 t][64 d]
        float4 kreg[8];
        #pragma unroll
        for (int j = 0; j < 8; j++) {
            int f = tid + 256 * j;           // 0..2047
            int r = f >> 4;                  // o = r>>4, t = r&15
            int dd = f & 15;
            kreg[j] = *(const float4*)&kbase[((size_t)(r >> 4) * TSEQ + t0 + (r & 15)) * HD + dd * 4];
        }
        float4 vreg = *(const float4*)&vbase[(size_t)(t0 + (tid >> 4)) * HD + (tid & 15) * 4];
        __syncthreads();                     // previous iteration fully done
        #pragma unroll
        for (int j = 0; j < 8; j++) {
            int f = tid + 256 * j;
            int r = f >> 4, dd = f & 15;
            *(float4*)&Ks[r * KPAD + dd * 4] = kreg[j];
        }
        *(float4*)&Vs[(tid >> 4) * KPAD + (tid & 15) * 4] = vreg;
        __syncthreads();

        // ---- phase 1: dots + MLP for positions (lrw, tt) and (lrw+16, tt)
        float acc0[8] = {0,0,0,0,0,0,0,0};
        float acc1[8] = {0,0,0,0,0,0,0,0};
        #pragma unroll
        for (int dd = 0; dd < 16; dd++) {
            float4 qa = *(const float4*)&Qs[lrw * KPAD + dd * 4];
            float4 qb4 = *(const float4*)&Qs[(lrw + 16) * KPAD + dd * 4];
            #pragma unroll
            for (int o = 0; o < 8; o++) {
                float4 k4 = *(const float4*)&Ks[(o * 16 + tt) * KPAD + dd * 4];
                acc0[o] = dot4f(qa,  k4, acc0[o]);
                acc1[o] = dot4f(qb4, k4, acc1[o]);
            }
        }
        float a0 = mlp_eval(acc0, b1r, w2r, b2r, w3r, b3r, w4r, b4r);
        float a1 = mlp_eval(acc1, b1r, w2r, b2r, w3r, b3r, w4r, b4r);
        As[lrw * 17 + tt]        = a0;
        As[(lrw + 16) * 17 + tt] = a1;
        __syncthreads();

        // ---- phase 2: O[l][d] += A[l][t] * V[t][d]
        #pragma unroll
        for (int t = 0; t < 16; t++) {
            float aa = As[lrw * 17 + t];
            float ab = As[(lrw + 16) * 17 + t];
            float4 v4 = *(const float4*)&Vs[t * KPAD + tt * 4];
            accA = fma4(aa, v4, accA);
            accB = fma4(ab, v4, accB);
        }
        // next-iteration barrier (top of loop) protects Ks/Vs/As overwrite
    }

    // store O: out[b][l0+lrw(+16)][h*64 + tt*4 ..]
    float* ob = out + ((size_t)b * TSEQ + l0) * E + h * HD;
    *(float4*)&ob[(size_t)lrw * E + tt * 4]        = accA;
    *(float4*)&ob[(size_t)(lrw + 16) * E + tt * 4] = accB;
}

// ---------------------------------------------------------------------------
extern "C" void kernel_launch(void* const* d_in, const int* in_sizes, int n_in,
                              void* d_out, int out_size, void* d_ws, size_t ws_size,
                              hipStream_t stream) {
    const float* x  = (const float*)d_in[0];
    const float* wq = (const float*)d_in[1];
    const float* bq = (const float*)d_in[2];
    const float* wk = (const float*)d_in[3];
    const float* bk = (const float*)d_in[4];
    const float* wv = (const float*)d_in[5];
    const float* bv = (const float*)d_in[6];
    const float* w1 = (const float*)d_in[7];
    const float* b1 = (const float*)d_in[8];
    const float* w2 = (const float*)d_in[9];
    const float* b2 = (const float*)d_in[10];
    const float* w3 = (const float*)d_in[11];
    const float* b3 = (const float*)d_in[12];
    const float* w4 = (const float*)d_in[13];
    const float* b4 = (const float*)d_in[14];
    float* out = (float*)d_out;

    float* ws = (float*)d_ws;
    float* Qb = ws;                    // 786432 floats [B,12,T,64]
    float* Kb = ws + 786432;           // 786432 floats [B,12,T,64]
    float* Vb = ws + 1572864;          // 786432 floats [B,12,T,64]
    float* Kp = ws + 2359296;          // 6291456 floats [B,12,8,T,64]

    qkv_kernel<<<dim3(16, 12, 3), 256, 0, stream>>>(x, wq, bq, wk, bk, wv, bv, Qb, Kb, Vb);
    kmix_kernel<<<6144, 256, 0, stream>>>(Kb, w1, Kp);
    attn_kernel<<<384, 256, 0, stream>>>(Qb, Kp, Vb, b1, w2, b2, w3, b3, w4, b4, out);
}

// Round 2
// 175.761 us; speedup vs baseline: 2.1853x; 2.1853x over previous
//
#include <hip/hip_runtime.h>

#define DEVINL __device__ __forceinline__

constexpr int E    = 768;
constexpr int TSEQ = 512;
constexpr int NH   = 12;
constexpr int HD   = 64;
constexpr float RSCALE = 0.036084391824351615f; // 1/sqrt(768)

typedef short bf16x8 __attribute__((ext_vector_type(8)));
typedef float floatx4 __attribute__((ext_vector_type(4)));

DEVINL short f2bf(float x) {
    union { float f; unsigned u; } v; v.f = x;
    unsigned r = v.u + 0x7FFFu + ((v.u >> 16) & 1u);
    return (short)(r >> 16);
}
DEVINL float bf2f(short s) {
    union { unsigned u; float f; } v;
    v.u = ((unsigned)(unsigned short)s) << 16;
    return v.f;
}

// ---------------------------------------------------------------------------
// Kernel 1: QKV projections (fp32 VALU GEMM), outputs bf16 [b][h][t][64].
// ---------------------------------------------------------------------------
__global__ __launch_bounds__(256) void qkv_kernel(
    const float* __restrict__ x,
    const float* __restrict__ wq, const float* __restrict__ bq,
    const float* __restrict__ wk, const float* __restrict__ bk,
    const float* __restrict__ wv, const float* __restrict__ bv,
    short* __restrict__ Qo, short* __restrict__ Ko, short* __restrict__ Vo)
{
    const float* W; const float* bias; short* outp;
    if (blockIdx.z == 0)      { W = wq; bias = bq; outp = Qo; }
    else if (blockIdx.z == 1) { W = wk; bias = bk; outp = Ko; }
    else                      { W = wv; bias = bv; outp = Vo; }

    __shared__ float xs[16][68];
    __shared__ float wls[16][68];

    const int m0  = blockIdx.x * 64;
    const int n0  = blockIdx.y * 64;
    const int tid = threadIdx.x;
    const int tx  = tid & 15;
    const int ty  = tid >> 4;
    const int lr  = tid >> 2;
    const int lc  = tid & 3;

    float acc[4][4] = {};

    for (int k0 = 0; k0 < E; k0 += 16) {
        float4 xv   = *(const float4*)&x[(size_t)(m0 + lr) * E + k0 + lc * 4];
        float4 wvec = *(const float4*)&W[(size_t)(n0 + lr) * E + k0 + lc * 4];
        __syncthreads();
        xs[lc*4+0][lr] = xv.x;  xs[lc*4+1][lr] = xv.y;
        xs[lc*4+2][lr] = xv.z;  xs[lc*4+3][lr] = xv.w;
        wls[lc*4+0][lr] = wvec.x; wls[lc*4+1][lr] = wvec.y;
        wls[lc*4+2][lr] = wvec.z; wls[lc*4+3][lr] = wvec.w;
        __syncthreads();
        #pragma unroll
        for (int k = 0; k < 16; k++) {
            float4 a4 = *(const float4*)&xs[k][ty*4];
            float4 b4 = *(const float4*)&wls[k][tx*4];
            float av[4] = {a4.x, a4.y, a4.z, a4.w};
            float bw[4] = {b4.x, b4.y, b4.z, b4.w};
            #pragma unroll
            for (int i = 0; i < 4; i++)
                #pragma unroll
                for (int j = 0; j < 4; j++)
                    acc[i][j] = fmaf(av[i], bw[j], acc[i][j]);
        }
    }

    float4 bv4 = *(const float4*)&bias[n0 + tx*4];
    const int bb = m0 / TSEQ;
    const int l  = (m0 % TSEQ) + ty*4;
    const int hh = n0 >> 6;
    short* ob = outp + ((size_t)(bb*NH + hh) * TSEQ) * HD;
    #pragma unroll
    for (int i = 0; i < 4; i++) {
        short4 r;
        r.x = f2bf(acc[i][0] + bv4.x);
        r.y = f2bf(acc[i][1] + bv4.y);
        r.z = f2bf(acc[i][2] + bv4.z);
        r.w = f2bf(acc[i][3] + bv4.w);
        *(short4*)&ob[(size_t)(l + i) * HD + tx*4] = r;
    }
}

// ---------------------------------------------------------------------------
// Kernel 2: Kp[b][h][o][t][d] = (1/scale) * sum_i w1[(h*8+o)*12+i] * K[b][i][t][d]
// bf16 in / bf16 out. One 8-element chunk per thread.
// ---------------------------------------------------------------------------
__global__ __launch_bounds__(256) void kmix_kernel(
    const short* __restrict__ K,   // [B,12,T,64] bf16
    const float* __restrict__ w1,  // [96,12] fp32
    short* __restrict__ Kp)        // [B,12,8,T,64] bf16
{
    const int g  = blockIdx.x * 256 + threadIdx.x;   // chunk of 8 bf16
    const int d8 = g & 7;
    const int t  = (g >> 3) & 511;
    const int o  = (g >> 12) & 7;
    const int bh = g >> 15;          // b*12 + h
    const int h  = bh % NH;
    const int b  = bh / NH;

    float acc[8] = {};
    #pragma unroll
    for (int i = 0; i < 12; i++) {
        float w = w1[(h*8 + o)*12 + i] * RSCALE;
        bf16x8 kv = *(const bf16x8*)&K[(((size_t)(b*NH + i) * TSEQ) + t) * HD + d8*8];
        #pragma unroll
        for (int j = 0; j < 8; j++)
            acc[j] = fmaf(w, bf2f(kv[j]), acc[j]);
    }
    bf16x8 outv;
    #pragma unroll
    for (int j = 0; j < 8; j++) outv[j] = f2bf(acc[j]);
    *(bf16x8*)&Kp[(size_t)g * 8] = outv;
}

// ---------------------------------------------------------------------------
// Per-position talking-heads MLP (conv1 weights folded into Kp; b1 here).
// ---------------------------------------------------------------------------
DEVINL float mlp_eval(const float s[8],
                      const float b1r[8], const float w2r[8], float b2r,
                      const float w3r[4], const float b3r[4],
                      const float w4r[4], float b4r)
{
    float z2 = b2r;
    #pragma unroll
    for (int o = 0; o < 8; o++) {
        float z1 = fmaxf(s[o] + b1r[o], 0.0f);
        z2 = fmaf(z1, w2r[o], z2);
    }
    float r = b4r;
    #pragma unroll
    for (int j = 0; j < 4; j++) {
        float z3 = fmaxf(fmaf(z2, w3r[j], b3r[j]), 0.0f);
        r = fmaf(z3, w4r[j], r);
    }
    return r;
}

// group-of-8 padded row offset (conflict-free transpose writes + aligned b128 reads)
DEVINL int vrow(int r) { return r*40 + (r >> 3)*8; }

// ---------------------------------------------------------------------------
// Kernel 3: MFMA attention. Block = (b, h, l-tile 64, t-quarter 128).
// 256 threads = 4 waves. Waves tiled 2(l-half) x 2(t-half) for S'.
// Writes partial O [64][64] fp32 per block; reduce kernel sums quarters.
// ---------------------------------------------------------------------------
__global__ __launch_bounds__(256, 3) void attn_mfma(
    const short* __restrict__ Qg,   // [B,12,T,64] bf16
    const short* __restrict__ Kg,   // [B,12,8,T,64] bf16
    const short* __restrict__ Vg,   // [B,12,T,64] bf16
    const float* __restrict__ b1, const float* __restrict__ w2,
    const float* __restrict__ b2, const float* __restrict__ w3,
    const float* __restrict__ b3, const float* __restrict__ w4,
    const float* __restrict__ b4,
    float* __restrict__ Pout)       // [768][64][64] fp32 partials
{
    __shared__ short Ks[256 * 72];   // [o*32+t][72]  (64d used)
    __shared__ short Vt[2624];       // transposed V: [d][t], group-padded
    __shared__ short As[2624];       // A weights:    [l][t], group-padded

    const int blk = blockIdx.x;          // ((b*12+h)*8+lt)*4 + qtr
    const int qtr = blk & 3;
    const int lt  = (blk >> 2) & 7;
    const int bh  = blk >> 5;
    const int h   = bh % NH;
    const int l0  = lt * 64;
    const int tb  = qtr * 128;

    const int tid  = threadIdx.x;
    const int wv   = tid >> 6;
    const int lane = tid & 63;
    const int col  = lane & 15;
    const int quad = lane >> 4;
    const int wl   = wv >> 1;   // l-half for S'
    const int wt   = wv & 1;    // t-half for S'

    // MLP weights (block-uniform)
    float b1r[8], w2r[8], w3r[4], b3r[4], w4r[4];
    #pragma unroll
    for (int o = 0; o < 8; o++) { b1r[o] = b1[h*8+o]; w2r[o] = w2[h*8+o]; }
    #pragma unroll
    for (int j = 0; j < 4; j++) { w3r[j] = w3[h*4+j]; b3r[j] = b3[h*4+j]; w4r[j] = w4[h*4+j]; }
    const float b2r = b2[h];
    const float b4r = b4[h];

    // Q A-fragments, register-resident for the whole kernel.
    // qa[li][k32]: A[m=lane&15][k=quad*8+j] for l-rows l0+wl*32+li*16+m, d=k32*32+k
    bf16x8 qa[2][2];
    {
        const short* qb = Qg + ((size_t)bh * TSEQ + l0 + wl*32 + col) * HD;
        qa[0][0] = *(const bf16x8*)&qb[quad*8];
        qa[0][1] = *(const bf16x8*)&qb[32 + quad*8];
        qa[1][0] = *(const bf16x8*)&qb[16*HD + quad*8];
        qa[1][1] = *(const bf16x8*)&qb[16*HD + 32 + quad*8];
    }

    floatx4 accO[4];
    #pragma unroll
    for (int d16 = 0; d16 < 4; d16++) accO[d16] = (floatx4){0.f, 0.f, 0.f, 0.f};

    const short* kbase = Kg + (size_t)bh * 8 * TSEQ * HD;
    const short* vbase = Vg + (size_t)bh * TSEQ * HD;

    const int tl = tid >> 3;   // 0..31 staging row
    const int dc = tid & 7;    // staging 16B chunk

    for (int it = 0; it < 4; it++) {
        const int t0 = tb + it * 32;

        // ---- global loads into registers
        bf16x8 ktmp[8];
        #pragma unroll
        for (int o = 0; o < 8; o++)
            ktmp[o] = *(const bf16x8*)&kbase[((size_t)o * TSEQ + t0 + tl) * HD + dc*8];
        bf16x8 vtmp = *(const bf16x8*)&vbase[(size_t)(t0 + tl) * HD + dc*8];

        __syncthreads();   // all reads of previous tile's Ks/Vt/As done

        #pragma unroll
        for (int o = 0; o < 8; o++)
            *(bf16x8*)&Ks[(o*32 + tl)*72 + dc*8] = ktmp[o];
        #pragma unroll
        for (int j = 0; j < 8; j++)
            Vt[vrow(dc*8 + j) + tl] = vtmp[j];   // transpose: Vt[d][t]

        __syncthreads();

        // ---- S' = Q . K''  (per wave: 16 t-cols (wt), 32 l-rows (wl), 8 o)
        floatx4 accS[8][2];
        #pragma unroll
        for (int o = 0; o < 8; o++) {
            accS[o][0] = (floatx4){0.f, 0.f, 0.f, 0.f};
            accS[o][1] = (floatx4){0.f, 0.f, 0.f, 0.f};
        }
        #pragma unroll
        for (int k32 = 0; k32 < 2; k32++) {
            #pragma unroll
            for (int o = 0; o < 8; o++) {
                bf16x8 bf = *(const bf16x8*)&Ks[(o*32 + wt*16 + col)*72 + k32*32 + quad*8];
                accS[o][0] = __builtin_amdgcn_mfma_f32_16x16x32_bf16(qa[0][k32], bf, accS[o][0], 0, 0, 0);
                accS[o][1] = __builtin_amdgcn_mfma_f32_16x16x32_bf16(qa[1][k32], bf, accS[o][1], 0, 0, 0);
            }
        }

        // ---- MLP on C-layout positions: row=quad*4+r (per li), col=t
        #pragma unroll
        for (int li = 0; li < 2; li++) {
            #pragma unroll
            for (int r = 0; r < 4; r++) {
                float s[8];
                #pragma unroll
                for (int o = 0; o < 8; o++) s[o] = accS[o][li][r];
                float a = mlp_eval(s, b1r, w2r, b2r, w3r, b3r, w4r, b4r);
                As[vrow(wl*32 + li*16 + quad*4 + r) + wt*16 + col] = f2bf(a);
            }
        }
        __syncthreads();

        // ---- O += A @ V  (per wave: 16 l-rows = wv*16.., K = 32 t)
        bf16x8 af = *(const bf16x8*)&As[vrow(wv*16 + col) + quad*8];
        #pragma unroll
        for (int d16 = 0; d16 < 4; d16++) {
            bf16x8 vf = *(const bf16x8*)&Vt[vrow(d16*16 + col) + quad*8];
            accO[d16] = __builtin_amdgcn_mfma_f32_16x16x32_bf16(af, vf, accO[d16], 0, 0, 0);
        }
    }

    // ---- store partial O: rows wv*16+quad*4+r, cols d16*16+col
    float* pb = Pout + (size_t)blk * 64 * 64;
    #pragma unroll
    for (int d16 = 0; d16 < 4; d16++)
        #pragma unroll
        for (int r = 0; r < 4; r++)
            pb[(wv*16 + quad*4 + r) * 64 + d16*16 + col] = accO[d16][r];
}

// ---------------------------------------------------------------------------
// Kernel 4: sum 4 t-quarter partials, scatter to out[b][l][h*64+d].
// ---------------------------------------------------------------------------
__global__ __launch_bounds__(256) void reduce_kernel(
    const float* __restrict__ P, float* __restrict__ out)
{
    const int gi  = blockIdx.x * 256 + threadIdx.x;  // float4 units, 196608 total
    const int d4  = gi & 15;
    const int r   = (gi >> 4) & 63;
    const int grp = gi >> 10;            // (b*12+h)*8 + lt
    const int lt  = grp & 7;
    const int bh  = grp >> 3;
    const int h   = bh % NH;
    const int b   = bh / NH;

    const float* p0 = P + (size_t)grp * 4 * 4096 + r * 64 + d4 * 4;
    float4 s0 = *(const float4*)&p0[0];
    float4 s1 = *(const float4*)&p0[4096];
    float4 s2 = *(const float4*)&p0[8192];
    float4 s3 = *(const float4*)&p0[12288];
    float4 s;
    s.x = (s0.x + s1.x) + (s2.x + s3.x);
    s.y = (s0.y + s1.y) + (s2.y + s3.y);
    s.z = (s0.z + s1.z) + (s2.z + s3.z);
    s.w = (s0.w + s1.w) + (s2.w + s3.w);
    *(float4*)&out[((size_t)(b*TSEQ + lt*64 + r)) * E + h*64 + d4*4] = s;
}

// ---------------------------------------------------------------------------
extern "C" void kernel_launch(void* const* d_in, const int* in_sizes, int n_in,
                              void* d_out, int out_size, void* d_ws, size_t ws_size,
                              hipStream_t stream) {
    const float* x  = (const float*)d_in[0];
    const float* wq = (const float*)d_in[1];
    const float* bq = (const float*)d_in[2];
    const float* wk = (const float*)d_in[3];
    const float* bk = (const float*)d_in[4];
    const float* wv = (const float*)d_in[5];
    const float* bv = (const float*)d_in[6];
    const float* w1 = (const float*)d_in[7];
    const float* b1 = (const float*)d_in[8];
    const float* w2 = (const float*)d_in[9];
    const float* b2 = (const float*)d_in[10];
    const float* w3 = (const float*)d_in[11];
    const float* b3 = (const float*)d_in[12];
    const float* w4 = (const float*)d_in[13];
    const float* b4 = (const float*)d_in[14];
    float* out = (float*)d_out;

    short* Qb = (short*)d_ws;                       // 786432 bf16
    short* Kb = Qb + 786432;                        // 786432 bf16
    short* Vb = Kb + 786432;                        // 786432 bf16
    short* Kp = Vb + 786432;                        // 6291456 bf16
    float* P  = (float*)(Kp + 6291456);             // 3145728 fp32 (17.3 MB offset)

    qkv_kernel<<<dim3(16, 12, 3), 256, 0, stream>>>(x, wq, bq, wk, bk, wv, bv, Qb, Kb, Vb);
    kmix_kernel<<<3072, 256, 0, stream>>>(Kb, w1, Kp);
    attn_mfma<<<768, 256, 0, stream>>>(Qb, Kp, Vb, b1, w2, b2, w3, b3, w4, b4, P);
    reduce_kernel<<<768, 256, 0, stream>>>(P, out);
}

// Round 3
// 132.143 us; speedup vs baseline: 2.9067x; 1.3301x over previous
//
#include <hip/hip_runtime.h>

#define DEVINL __device__ __forceinline__

constexpr int E    = 768;
constexpr int TSEQ = 512;
constexpr int NH   = 12;
constexpr int HD   = 64;
constexpr float RSCALE = 0.036084391824351615f; // 1/sqrt(768)

typedef short bf16x8 __attribute__((ext_vector_type(8)));
typedef float floatx4 __attribute__((ext_vector_type(4)));

DEVINL short f2bf(float x) {
    union { float f; unsigned u; } v; v.f = x;
    unsigned r = v.u + 0x7FFFu + ((v.u >> 16) & 1u);
    return (short)(r >> 16);
}
DEVINL float bf2f(short s) {
    union { unsigned u; float f; } v;
    v.u = ((unsigned)(unsigned short)s) << 16;
    return v.f;
}

// ---------------------------------------------------------------------------
// Kernel 0: fp32 -> bf16 conversion for x, wq, wk, wv (one pass).
// 8 elements per thread.
// ---------------------------------------------------------------------------
__global__ __launch_bounds__(256) void convert_kernel(
    const float* __restrict__ x,  const float* __restrict__ wq,
    const float* __restrict__ wk, const float* __restrict__ wv,
    short* __restrict__ xb, short* __restrict__ wqb,
    short* __restrict__ wkb, short* __restrict__ wvb)
{
    const int g = blockIdx.x * 256 + threadIdx.x;    // 319488 threads total
    const float* src; short* dst; int off;
    if (g < 98304)       { src = x;  dst = xb;  off = g * 8; }
    else if (g < 172032) { src = wq; dst = wqb; off = (g - 98304) * 8; }
    else if (g < 245760) { src = wk; dst = wkb; off = (g - 172032) * 8; }
    else                 { src = wv; dst = wvb; off = (g - 245760) * 8; }
    float4 f0 = *(const float4*)&src[off];
    float4 f1 = *(const float4*)&src[off + 4];
    bf16x8 o;
    o[0] = f2bf(f0.x); o[1] = f2bf(f0.y); o[2] = f2bf(f0.z); o[3] = f2bf(f0.w);
    o[4] = f2bf(f1.x); o[5] = f2bf(f1.y); o[6] = f2bf(f1.z); o[7] = f2bf(f1.w);
    *(bf16x8*)&dst[off] = o;
}

// ---------------------------------------------------------------------------
// Kernel 1: QKV projections via MFMA.  y = x @ W^T + b  (bf16 in, bf16 out,
// fp32 accum).  Block = 64x64 output tile (one head wide), 4 waves.
// Wave w owns n-columns [w*16, w*16+16); all waves sweep 4 m-subtiles.
// LDS rows padded to 72 bf16 -> balanced banks for b128 reads/writes.
// ---------------------------------------------------------------------------
__global__ __launch_bounds__(256) void qkv_mfma(
    const short* __restrict__ xb,
    const short* __restrict__ wqb, const float* __restrict__ bq,
    const short* __restrict__ wkb, const float* __restrict__ bk,
    const short* __restrict__ wvb, const float* __restrict__ bv,
    short* __restrict__ Qo, short* __restrict__ Ko, short* __restrict__ Vo)
{
    const short* W; const float* bias; short* outp;
    if (blockIdx.z == 0)      { W = wqb; bias = bq; outp = Qo; }
    else if (blockIdx.z == 1) { W = wkb; bias = bk; outp = Ko; }
    else                      { W = wvb; bias = bv; outp = Vo; }

    __shared__ short As[64 * 72];
    __shared__ short Bs[64 * 72];

    const int m0   = blockIdx.x * 64;
    const int n0   = blockIdx.y * 64;    // == head * 64
    const int tid  = threadIdx.x;
    const int wvi  = tid >> 6;
    const int lane = tid & 63;
    const int col  = lane & 15;
    const int quad = lane >> 4;

    // staging chunks: c and c+256; row = c>>3, kchunk = c&7
    const int r0 = tid >> 3,   kc0 = tid & 7;
    const int r1 = r0 + 32;    // (tid+256)>>3

    floatx4 acc[4];
    #pragma unroll
    for (int i = 0; i < 4; i++) acc[i] = (floatx4){0.f, 0.f, 0.f, 0.f};

    for (int k0 = 0; k0 < E; k0 += 64) {
        bf16x8 a0 = *(const bf16x8*)&xb[(size_t)(m0 + r0) * E + k0 + kc0 * 8];
        bf16x8 a1 = *(const bf16x8*)&xb[(size_t)(m0 + r1) * E + k0 + kc0 * 8];
        bf16x8 b0 = *(const bf16x8*)&W [(size_t)(n0 + r0) * E + k0 + kc0 * 8];
        bf16x8 b1 = *(const bf16x8*)&W [(size_t)(n0 + r1) * E + k0 + kc0 * 8];
        __syncthreads();
        *(bf16x8*)&As[r0 * 72 + kc0 * 8] = a0;
        *(bf16x8*)&As[r1 * 72 + kc0 * 8] = a1;
        *(bf16x8*)&Bs[r0 * 72 + kc0 * 8] = b0;
        *(bf16x8*)&Bs[r1 * 72 + kc0 * 8] = b1;
        __syncthreads();
        #pragma unroll
        for (int k32 = 0; k32 < 2; k32++) {
            bf16x8 bf = *(const bf16x8*)&Bs[(wvi*16 + col) * 72 + k32*32 + quad*8];
            #pragma unroll
            for (int ms = 0; ms < 4; ms++) {
                bf16x8 af = *(const bf16x8*)&As[(ms*16 + col) * 72 + k32*32 + quad*8];
                acc[ms] = __builtin_amdgcn_mfma_f32_16x16x32_bf16(af, bf, acc[ms], 0, 0, 0);
            }
        }
    }

    // epilogue: C layout row = quad*4+r, col = lane&15 (n within wave slice)
    const float bn = bias[n0 + wvi*16 + col];
    const int h = blockIdx.y;
    #pragma unroll
    for (int ms = 0; ms < 4; ms++) {
        #pragma unroll
        for (int r = 0; r < 4; r++) {
            int m = m0 + ms*16 + quad*4 + r;
            int bb = m >> 9, l = m & 511;
            outp[(((size_t)(bb*NH + h)) * TSEQ + l) * HD + wvi*16 + col] =
                f2bf(acc[ms][r] + bn);
        }
    }
}

// ---------------------------------------------------------------------------
// Kernel 2: Kp[b][h][o][t][d] = (1/scale) * sum_i w1[(h*8+o)*12+i] * K[b][i][t][d]
// ---------------------------------------------------------------------------
__global__ __launch_bounds__(256) void kmix_kernel(
    const short* __restrict__ K,   // [B,12,T,64] bf16
    const float* __restrict__ w1,  // [96,12] fp32
    short* __restrict__ Kp)        // [B,12,8,T,64] bf16
{
    const int g  = blockIdx.x * 256 + threadIdx.x;   // chunk of 8 bf16
    const int d8 = g & 7;
    const int t  = (g >> 3) & 511;
    const int o  = (g >> 12) & 7;
    const int bh = g >> 15;          // b*12 + h
    const int h  = bh % NH;
    const int b  = bh / NH;

    float acc[8] = {};
    #pragma unroll
    for (int i = 0; i < 12; i++) {
        float w = w1[(h*8 + o)*12 + i] * RSCALE;
        bf16x8 kv = *(const bf16x8*)&K[(((size_t)(b*NH + i) * TSEQ) + t) * HD + d8*8];
        #pragma unroll
        for (int j = 0; j < 8; j++)
            acc[j] = fmaf(w, bf2f(kv[j]), acc[j]);
    }
    bf16x8 outv;
    #pragma unroll
    for (int j = 0; j < 8; j++) outv[j] = f2bf(acc[j]);
    *(bf16x8*)&Kp[(size_t)g * 8] = outv;
}

// ---------------------------------------------------------------------------
// Per-position talking-heads MLP (conv1 weights folded into Kp; b1 here).
// ---------------------------------------------------------------------------
DEVINL float mlp_eval(const float s[8],
                      const float b1r[8], const float w2r[8], float b2r,
                      const float w3r[4], const float b3r[4],
                      const float w4r[4], float b4r)
{
    float z2 = b2r;
    #pragma unroll
    for (int o = 0; o < 8; o++) {
        float z1 = fmaxf(s[o] + b1r[o], 0.0f);
        z2 = fmaf(z1, w2r[o], z2);
    }
    float r = b4r;
    #pragma unroll
    for (int j = 0; j < 4; j++) {
        float z3 = fmaxf(fmaf(z2, w3r[j], b3r[j]), 0.0f);
        r = fmaf(z3, w4r[j], r);
    }
    return r;
}

// group-of-8 padded row offset (conflict-free transpose writes + aligned b128 reads)
DEVINL int vrow(int r) { return r*40 + (r >> 3)*8; }

// ---------------------------------------------------------------------------
// Kernel 3: MFMA attention. Block = (b, h, l-tile 64, t-quarter 128).
// ---------------------------------------------------------------------------
__global__ __launch_bounds__(256, 3) void attn_mfma(
    const short* __restrict__ Qg,   // [B,12,T,64] bf16
    const short* __restrict__ Kg,   // [B,12,8,T,64] bf16
    const short* __restrict__ Vg,   // [B,12,T,64] bf16
    const float* __restrict__ b1, const float* __restrict__ w2,
    const float* __restrict__ b2, const float* __restrict__ w3,
    const float* __restrict__ b3, const float* __restrict__ w4,
    const float* __restrict__ b4,
    float* __restrict__ Pout)       // [768][64][64] fp32 partials
{
    __shared__ short Ks[256 * 72];   // [o*32+t][72]  (64d used)
    __shared__ short Vt[2624];       // transposed V: [d][t], group-padded
    __shared__ short As[2624];       // A weights:    [l][t], group-padded

    const int blk = blockIdx.x;          // ((b*12+h)*8+lt)*4 + qtr
    const int qtr = blk & 3;
    const int lt  = (blk >> 2) & 7;
    const int bh  = blk >> 5;
    const int h   = bh % NH;
    const int l0  = lt * 64;
    const int tb  = qtr * 128;

    const int tid  = threadIdx.x;
    const int wv   = tid >> 6;
    const int lane = tid & 63;
    const int col  = lane & 15;
    const int quad = lane >> 4;
    const int wl   = wv >> 1;   // l-half for S'
    const int wt   = wv & 1;    // t-half for S'

    float b1r[8], w2r[8], w3r[4], b3r[4], w4r[4];
    #pragma unroll
    for (int o = 0; o < 8; o++) { b1r[o] = b1[h*8+o]; w2r[o] = w2[h*8+o]; }
    #pragma unroll
    for (int j = 0; j < 4; j++) { w3r[j] = w3[h*4+j]; b3r[j] = b3[h*4+j]; w4r[j] = w4[h*4+j]; }
    const float b2r = b2[h];
    const float b4r = b4[h];

    bf16x8 qa[2][2];
    {
        const short* qb = Qg + ((size_t)bh * TSEQ + l0 + wl*32 + col) * HD;
        qa[0][0] = *(const bf16x8*)&qb[quad*8];
        qa[0][1] = *(const bf16x8*)&qb[32 + quad*8];
        qa[1][0] = *(const bf16x8*)&qb[16*HD + quad*8];
        qa[1][1] = *(const bf16x8*)&qb[16*HD + 32 + quad*8];
    }

    floatx4 accO[4];
    #pragma unroll
    for (int d16 = 0; d16 < 4; d16++) accO[d16] = (floatx4){0.f, 0.f, 0.f, 0.f};

    const short* kbase = Kg + (size_t)bh * 8 * TSEQ * HD;
    const short* vbase = Vg + (size_t)bh * TSEQ * HD;

    const int tl = tid >> 3;   // 0..31 staging row
    const int dc = tid & 7;    // staging 16B chunk

    for (int it = 0; it < 4; it++) {
        const int t0 = tb + it * 32;

        bf16x8 ktmp[8];
        #pragma unroll
        for (int o = 0; o < 8; o++)
            ktmp[o] = *(const bf16x8*)&kbase[((size_t)o * TSEQ + t0 + tl) * HD + dc*8];
        bf16x8 vtmp = *(const bf16x8*)&vbase[(size_t)(t0 + tl) * HD + dc*8];

        __syncthreads();

        #pragma unroll
        for (int o = 0; o < 8; o++)
            *(bf16x8*)&Ks[(o*32 + tl)*72 + dc*8] = ktmp[o];
        #pragma unroll
        for (int j = 0; j < 8; j++)
            Vt[vrow(dc*8 + j) + tl] = vtmp[j];   // transpose: Vt[d][t]

        __syncthreads();

        floatx4 accS[8][2];
        #pragma unroll
        for (int o = 0; o < 8; o++) {
            accS[o][0] = (floatx4){0.f, 0.f, 0.f, 0.f};
            accS[o][1] = (floatx4){0.f, 0.f, 0.f, 0.f};
        }
        #pragma unroll
        for (int k32 = 0; k32 < 2; k32++) {
            #pragma unroll
            for (int o = 0; o < 8; o++) {
                bf16x8 bf = *(const bf16x8*)&Ks[(o*32 + wt*16 + col)*72 + k32*32 + quad*8];
                accS[o][0] = __builtin_amdgcn_mfma_f32_16x16x32_bf16(qa[0][k32], bf, accS[o][0], 0, 0, 0);
                accS[o][1] = __builtin_amdgcn_mfma_f32_16x16x32_bf16(qa[1][k32], bf, accS[o][1], 0, 0, 0);
            }
        }

        #pragma unroll
        for (int li = 0; li < 2; li++) {
            #pragma unroll
            for (int r = 0; r < 4; r++) {
                float s[8];
                #pragma unroll
                for (int o = 0; o < 8; o++) s[o] = accS[o][li][r];
                float a = mlp_eval(s, b1r, w2r, b2r, w3r, b3r, w4r, b4r);
                As[vrow(wl*32 + li*16 + quad*4 + r) + wt*16 + col] = f2bf(a);
            }
        }
        __syncthreads();

        bf16x8 af = *(const bf16x8*)&As[vrow(wv*16 + col) + quad*8];
        #pragma unroll
        for (int d16 = 0; d16 < 4; d16++) {
            bf16x8 vf = *(const bf16x8*)&Vt[vrow(d16*16 + col) + quad*8];
            accO[d16] = __builtin_amdgcn_mfma_f32_16x16x32_bf16(af, vf, accO[d16], 0, 0, 0);
        }
    }

    float* pb = Pout + (size_t)blk * 64 * 64;
    #pragma unroll
    for (int d16 = 0; d16 < 4; d16++)
        #pragma unroll
        for (int r = 0; r < 4; r++)
            pb[(wv*16 + quad*4 + r) * 64 + d16*16 + col] = accO[d16][r];
}

// ---------------------------------------------------------------------------
// Kernel 4: sum 4 t-quarter partials, scatter to out[b][l][h*64+d].
// ---------------------------------------------------------------------------
__global__ __launch_bounds__(256) void reduce_kernel(
    const float* __restrict__ P, float* __restrict__ out)
{
    const int gi  = blockIdx.x * 256 + threadIdx.x;  // float4 units, 196608 total
    const int d4  = gi & 15;
    const int r   = (gi >> 4) & 63;
    const int grp = gi >> 10;            // (b*12+h)*8 + lt
    const int lt  = grp & 7;
    const int bh  = grp >> 3;
    const int h   = bh % NH;
    const int b   = bh / NH;

    const float* p0 = P + (size_t)grp * 4 * 4096 + r * 64 + d4 * 4;
    float4 s0 = *(const float4*)&p0[0];
    float4 s1 = *(const float4*)&p0[4096];
    float4 s2 = *(const float4*)&p0[8192];
    float4 s3 = *(const float4*)&p0[12288];
    float4 s;
    s.x = (s0.x + s1.x) + (s2.x + s3.x);
    s.y = (s0.y + s1.y) + (s2.y + s3.y);
    s.z = (s0.z + s1.z) + (s2.z + s3.z);
    s.w = (s0.w + s1.w) + (s2.w + s3.w);
    *(float4*)&out[((size_t)(b*TSEQ + lt*64 + r)) * E + h*64 + d4*4] = s;
}

// ---------------------------------------------------------------------------
extern "C" void kernel_launch(void* const* d_in, const int* in_sizes, int n_in,
                              void* d_out, int out_size, void* d_ws, size_t ws_size,
                              hipStream_t stream) {
    const float* x  = (const float*)d_in[0];
    const float* wq = (const float*)d_in[1];
    const float* bq = (const float*)d_in[2];
    const float* wk = (const float*)d_in[3];
    const float* bk = (const float*)d_in[4];
    const float* wv = (const float*)d_in[5];
    const float* bv = (const float*)d_in[6];
    const float* w1 = (const float*)d_in[7];
    const float* b1 = (const float*)d_in[8];
    const float* w2 = (const float*)d_in[9];
    const float* b2 = (const float*)d_in[10];
    const float* w3 = (const float*)d_in[11];
    const float* b3 = (const float*)d_in[12];
    const float* w4 = (const float*)d_in[13];
    const float* b4 = (const float*)d_in[14];
    float* out = (float*)d_out;

    short* Qb = (short*)d_ws;                       // 786432 bf16
    short* Kb = Qb + 786432;                        // 786432 bf16
    short* Vb = Kb + 786432;                        // 786432 bf16
    short* Kp = Vb + 786432;                        // 6291456 bf16
    float* P  = (float*)(Kp + 6291456);             // 3145728 fp32
    // bf16 conversions of x/wq/wk/wv alias the P region (P is written later)
    short* xb  = (short*)P;                         // 786432 bf16
    short* wqb = xb + 786432;                       // 589824 bf16
    short* wkb = wqb + 589824;
    short* wvb = wkb + 589824;

    convert_kernel<<<1248, 256, 0, stream>>>(x, wq, wk, wv, xb, wqb, wkb, wvb);
    qkv_mfma<<<dim3(16, 12, 3), 256, 0, stream>>>(xb, wqb, bq, wkb, bk, wvb, bv, Qb, Kb, Vb);
    kmix_kernel<<<3072, 256, 0, stream>>>(Kb, w1, Kp);
    attn_mfma<<<768, 256, 0, stream>>>(Qb, Kp, Vb, b1, w2, b2, w3, b3, w4, b4, P);
    reduce_kernel<<<768, 256, 0, stream>>>(P, out);
}